// Round 4
// baseline (1063.670 us; speedup 1.0000x reference)
//
#include <hip/hip_runtime.h>
#include <math.h>

typedef short short8 __attribute__((ext_vector_type(8)));
typedef short short4v __attribute__((ext_vector_type(4)));
typedef float f32x4 __attribute__((ext_vector_type(4)));
typedef unsigned short u16;
typedef unsigned int u32;

#define S_TOK 4096
#define DM 768
#define DF 3072
#define NE 8
#define NSLOT (S_TOK*2)   // 8192 (token,expert) slots

// ---- control block (first 256 KB of ws) ----
#define WS_COUNTS   0                         // 8 ints
#define WS_CURSOR   64                        // 8 ints
#define WS_OFFS     128                       // 9 ints
#define WS_FLAG     192                       // 1 int (0=bf16 inputs, 1=fp32 inputs)
#define WS_EID      256                       // NSLOT ints
#define WS_GW       (WS_EID  + NSLOT*4)       // NSLOT floats
#define WS_TOK      (WS_GW   + NSLOT*4)       // NSLOT ints
#define WS_WOF      (WS_TOK  + NSLOT*4)       // NSLOT floats
#define WS_POS      (WS_WOF  + NSLOT*4)       // NSLOT ints  (ends at 164 KB)
#define CTRL_BYTES  262144

__device__ inline float b2f(u16 v){ u32 u = ((u32)v) << 16; return __builtin_bit_cast(float, u); }
__device__ inline u16 f2b(float f){
    u32 u = __builtin_bit_cast(u32, f);
    u32 r = (u + 0x7fffu + ((u >> 16) & 1u)) >> 16;   // RNE
    return (u16)r;
}
__device__ inline short8 ldcvt8f(const float* p){   // 8 fp32 -> short8 bf16
    float4 a = *(const float4*)p;
    float4 b = *(const float4*)(p + 4);
    short8 v;
    v[0]=(short)f2b(a.x); v[1]=(short)f2b(a.y); v[2]=(short)f2b(a.z); v[3]=(short)f2b(a.w);
    v[4]=(short)f2b(b.x); v[5]=(short)f2b(b.y); v[6]=(short)f2b(b.z); v[7]=(short)f2b(b.w);
    return v;
}

// ---------------- dtype probe: even-index u16s of x are bf16 values (bf16-reality)
// or uniform fp32 mantissa bits (fp32-reality). Count exponent-field outliers. ----------------
__global__ __launch_bounds__(256) void probe_kernel(const u16* __restrict__ xu, int* __restrict__ flag){
    __shared__ int cnt;
    if (threadIdx.x == 0) cnt = 0;
    __syncthreads();
    int t = threadIdx.x;
    int local = 0;
#pragma unroll
    for (int i = 0; i < 8; i++){
        u16 v = xu[(t*8 + i)*2];          // first 8 KB of x; in-bounds either way
        int ex = (v >> 7) & 0xFF;
        if (ex < 100 || ex > 150) local++;
    }
    atomicAdd(&cnt, local);
    __syncthreads();
    if (t == 0) *flag = (cnt > 256) ? 1 : 0;
}

// ---------------- init: zero counts + cursor ----------------
__global__ void init2_kernel(int* __restrict__ counts, int* __restrict__ cursor){
    int t = threadIdx.x;
    if (t < 8){ counts[t] = 0; cursor[t] = 0; }
}

// ---------------- gate: logits -> top2 -> weights ----------------
__global__ __launch_bounds__(64) void gate_kernel(const void* __restrict__ x_, const void* __restrict__ wg_,
                                                  const int* __restrict__ flag,
                                                  int* __restrict__ eid, float* __restrict__ gw,
                                                  int* __restrict__ counts){
    int s = blockIdx.x;
    int l = threadIdx.x;
    int fl = *flag;
    float acc[NE];
#pragma unroll
    for (int e = 0; e < NE; e++) acc[e] = 0.f;
    if (fl){
        const float* xr = (const float*)x_ + (size_t)s * DM;
        const float* Wg = (const float*)wg_;
#pragma unroll
        for (int i = 0; i < DM/64; i++){
            int d = l + 64*i;
            float xv = xr[d];
            float4 w0 = *(const float4*)(Wg + d*NE);
            float4 w1 = *(const float4*)(Wg + d*NE + 4);
            acc[0] += xv*w0.x; acc[1] += xv*w0.y; acc[2] += xv*w0.z; acc[3] += xv*w0.w;
            acc[4] += xv*w1.x; acc[5] += xv*w1.y; acc[6] += xv*w1.z; acc[7] += xv*w1.w;
        }
    } else {
        const u16* xr = (const u16*)x_ + (size_t)s * DM;
        const u16* Wg = (const u16*)wg_;
#pragma unroll
        for (int i = 0; i < DM/64; i++){
            int d = l + 64*i;
            float xv = b2f(xr[d]);
            short8 wr = *(const short8*)(Wg + d*NE);
#pragma unroll
            for (int e = 0; e < NE; e++) acc[e] += xv * b2f((u16)wr[e]);
        }
    }
#pragma unroll
    for (int e = 0; e < NE; e++){
#pragma unroll
        for (int off = 32; off; off >>= 1) acc[e] += __shfl_down(acc[e], off);
    }
    if (l == 0){
        int i1 = 0; float v1 = acc[0];
        for (int e = 1; e < NE; e++) if (acc[e] > v1){ v1 = acc[e]; i1 = e; }
        int i2 = -1; float v2 = -1e30f;
        for (int e = 0; e < NE; e++) if (e != i1 && acc[e] > v2){ v2 = acc[e]; i2 = e; }
        float w0, w1;
        if (i2 < 0){ i2 = (i1 + 1) & 7; w0 = 1.f; w1 = 0.f; }   // NaN-safe guard
        else {
            float e2 = expf(v2 - v1);
            w0 = 1.f / (1.f + e2);
            w1 = e2 / (1.f + e2);
        }
        eid[2*s]   = i1; gw[2*s]   = w0;
        eid[2*s+1] = i2; gw[2*s+1] = w1;
        atomicAdd(&counts[i1], 1);
        atomicAdd(&counts[i2], 1);
    }
}

__global__ void offsets_kernel(const int* __restrict__ counts, int* __restrict__ offs, int* __restrict__ cursor){
    if (threadIdx.x == 0 && blockIdx.x == 0){
        int s = 0;
        for (int e = 0; e < NE; e++){ offs[e] = s; cursor[e] = s; s += counts[e]; }
        offs[NE] = s;
    }
}

__global__ __launch_bounds__(256) void scatter_kernel(const int* __restrict__ eid, const float* __restrict__ gw,
                                                      int* __restrict__ cursor, int* __restrict__ tok_of,
                                                      float* __restrict__ w_of, int* __restrict__ pos_of){
    int i = blockIdx.x*256 + threadIdx.x;
    int e = eid[i];
    if (e < 0) e = 0; if (e > 7) e = 7;               // wild-index insurance
    int p = atomicAdd(&cursor[e], 1);
    if (p < 0) p = 0; if (p >= NSLOT) p = NSLOT - 1;
    tok_of[p] = i >> 1;
    w_of[p]  = gw[i];
    pos_of[i] = p;
}

// ---------------- GEMM1 (grouped): h = relu(x[tok] @ W1[e] + b1[e]), h bf16 ----------------
__global__ __launch_bounds__(256) void gemm1g_kernel(const void* __restrict__ x_, const int* __restrict__ tok_of,
                                                     const int* __restrict__ offs, const void* __restrict__ w1_,
                                                     const void* __restrict__ b1_, const int* __restrict__ flag,
                                                     u16* __restrict__ h, int s0, int s1, int MB){
    const int KB = DM/32;   // 24
    int e  = blockIdx.x / MB;
    int mb = blockIdx.x % MB;
    int lo = offs[e];   if (lo < s0) lo = s0;
    int hi = offs[e+1]; if (hi > s1) hi = s1;
    int m0 = lo + mb*128;
    if (m0 >= hi) return;
    int n0 = blockIdx.y * 128;
    int fl = *flag;

    int t = threadIdx.x;
    int w = t >> 6, l = t & 63;
    int wm = w & 1, wn = w >> 1;

    __shared__ u16 As[128*40];
    __shared__ u16 Bs[32*136];

    int row0 = t >> 2, kc = t & 3;
    int r0 = m0 + row0;        if (r0 > hi-1) r0 = hi-1;
    int r1 = m0 + row0 + 64;   if (r1 > hi-1) r1 = hi-1;
    size_t aoff0 = (size_t)tok_of[r0] * DM + kc*8;
    size_t aoff1 = (size_t)tok_of[r1] * DM + kc*8;
    u16* as0 = &As[row0*40 + kc*8];
    u16* as1 = &As[(row0 + 64)*40 + kc*8];

    int k0s = t >> 4, ncs = t & 15;
    size_t wbase = (size_t)e * DM * DF;

    f32x4 acc[4][4];
#pragma unroll
    for (int i = 0; i < 4; i++)
#pragma unroll
        for (int j = 0; j < 4; j++) acc[i][j] = (f32x4){0.f, 0.f, 0.f, 0.f};

    for (int kb = 0; kb < KB; kb++){
        short8 av0, av1, bv0, bv1;
        if (fl){
            const float* xf = (const float*)x_;
            const float* wf = (const float*)w1_ + wbase;
            av0 = ldcvt8f(xf + aoff0 + kb*32);
            av1 = ldcvt8f(xf + aoff1 + kb*32);
            bv0 = ldcvt8f(wf + (size_t)(kb*32 + k0s)*DF + n0 + ncs*8);
            bv1 = ldcvt8f(wf + (size_t)(kb*32 + k0s + 16)*DF + n0 + ncs*8);
        } else {
            const u16* xb = (const u16*)x_;
            const u16* wb = (const u16*)w1_ + wbase;
            av0 = *(const short8*)(xb + aoff0 + kb*32);
            av1 = *(const short8*)(xb + aoff1 + kb*32);
            bv0 = *(const short8*)&wb[(size_t)(kb*32 + k0s)*DF + n0 + ncs*8];
            bv1 = *(const short8*)&wb[(size_t)(kb*32 + k0s + 16)*DF + n0 + ncs*8];
        }
        *(short8*)as0 = av0;
        *(short8*)as1 = av1;
        *(short8*)&Bs[k0s*136 + ncs*8] = bv0;
        *(short8*)&Bs[(k0s + 16)*136 + ncs*8] = bv1;
        __syncthreads();
        short8 af[4], bf[4];
#pragma unroll
        for (int mt = 0; mt < 4; mt++)
            af[mt] = *(const short8*)&As[(wm*64 + mt*16 + (l & 15))*40 + (l >> 4)*8];
#pragma unroll
        for (int nt = 0; nt < 4; nt++){
            int nl = wn*64 + nt*16 + (l & 15);
            short8 v;
#pragma unroll
            for (int j = 0; j < 8; j++) v[j] = (short)Bs[((l >> 4)*8 + j)*136 + nl];
            bf[nt] = v;
        }
#pragma unroll
        for (int mt = 0; mt < 4; mt++)
#pragma unroll
            for (int nt = 0; nt < 4; nt++)
                acc[mt][nt] = __builtin_amdgcn_mfma_f32_16x16x32_bf16(af[mt], bf[nt], acc[mt][nt], 0, 0, 0);
        __syncthreads();
    }

#pragma unroll
    for (int nt = 0; nt < 4; nt++){
        int col = n0 + wn*64 + nt*16 + (l & 15);
        float bv = fl ? ((const float*)b1_)[e*DF + col] : b2f(((const u16*)b1_)[e*DF + col]);
#pragma unroll
        for (int mt = 0; mt < 4; mt++){
#pragma unroll
            for (int r = 0; r < 4; r++){
                int grow = m0 + wm*64 + mt*16 + (l >> 4)*4 + r;
                if (grow < hi){
                    float v = acc[mt][nt][r] + bv;
                    v = v > 0.f ? v : 0.f;
                    h[(size_t)(grow - s0)*DF + col] = f2b(v);
                }
            }
        }
    }
}

// ---------------- GEMM2 (grouped): so = w * (h @ W2[e] + b2[e]), so fp32 ----------------
__global__ __launch_bounds__(256) void gemm2g_kernel(const u16* __restrict__ h, const int* __restrict__ offs,
                                                     const void* __restrict__ w2_, const void* __restrict__ b2_,
                                                     const int* __restrict__ flag,
                                                     const float* __restrict__ w_of, float* __restrict__ so,
                                                     int s0, int s1, int MB){
    const int KB = DF/32;   // 96
    int e  = blockIdx.x / MB;
    int mb = blockIdx.x % MB;
    int lo = offs[e];   if (lo < s0) lo = s0;
    int hi = offs[e+1]; if (hi > s1) hi = s1;
    int m0 = lo + mb*128;
    if (m0 >= hi) return;
    int n0 = blockIdx.y * 128;
    int fl = *flag;

    int t = threadIdx.x;
    int w = t >> 6, l = t & 63;
    int wm = w & 1, wn = w >> 1;

    __shared__ u16 As[128*40];
    __shared__ u16 Bs[32*136];

    int row0 = t >> 2, kc = t & 3;
    int r0 = m0 + row0;        if (r0 > hi-1) r0 = hi-1;
    int r1 = m0 + row0 + 64;   if (r1 > hi-1) r1 = hi-1;
    const u16* a0 = h + (size_t)(r0 - s0) * DF + kc*8;
    const u16* a1 = h + (size_t)(r1 - s0) * DF + kc*8;
    u16* as0 = &As[row0*40 + kc*8];
    u16* as1 = &As[(row0 + 64)*40 + kc*8];

    int k0s = t >> 4, ncs = t & 15;
    size_t wbase = (size_t)e * DF * DM;

    f32x4 acc[4][4];
#pragma unroll
    for (int i = 0; i < 4; i++)
#pragma unroll
        for (int j = 0; j < 4; j++) acc[i][j] = (f32x4){0.f, 0.f, 0.f, 0.f};

    for (int kb = 0; kb < KB; kb++){
        short8 av0 = *(const short8*)(a0 + kb*32);
        short8 av1 = *(const short8*)(a1 + kb*32);
        short8 bv0, bv1;
        if (fl){
            const float* wf = (const float*)w2_ + wbase;
            bv0 = ldcvt8f(wf + (size_t)(kb*32 + k0s)*DM + n0 + ncs*8);
            bv1 = ldcvt8f(wf + (size_t)(kb*32 + k0s + 16)*DM + n0 + ncs*8);
        } else {
            const u16* wb = (const u16*)w2_ + wbase;
            bv0 = *(const short8*)&wb[(size_t)(kb*32 + k0s)*DM + n0 + ncs*8];
            bv1 = *(const short8*)&wb[(size_t)(kb*32 + k0s + 16)*DM + n0 + ncs*8];
        }
        *(short8*)as0 = av0;
        *(short8*)as1 = av1;
        *(short8*)&Bs[k0s*136 + ncs*8] = bv0;
        *(short8*)&Bs[(k0s + 16)*136 + ncs*8] = bv1;
        __syncthreads();
        short8 af[4], bf[4];
#pragma unroll
        for (int mt = 0; mt < 4; mt++)
            af[mt] = *(const short8*)&As[(wm*64 + mt*16 + (l & 15))*40 + (l >> 4)*8];
#pragma unroll
        for (int nt = 0; nt < 4; nt++){
            int nl = wn*64 + nt*16 + (l & 15);
            short8 v;
#pragma unroll
            for (int j = 0; j < 8; j++) v[j] = (short)Bs[((l >> 4)*8 + j)*136 + nl];
            bf[nt] = v;
        }
#pragma unroll
        for (int mt = 0; mt < 4; mt++)
#pragma unroll
            for (int nt = 0; nt < 4; nt++)
                acc[mt][nt] = __builtin_amdgcn_mfma_f32_16x16x32_bf16(af[mt], bf[nt], acc[mt][nt], 0, 0, 0);
        __syncthreads();
    }

#pragma unroll
    for (int nt = 0; nt < 4; nt++){
        int col = n0 + wn*64 + nt*16 + (l & 15);
        float bv = fl ? ((const float*)b2_)[e*DM + col] : b2f(((const u16*)b2_)[e*DM + col]);
#pragma unroll
        for (int mt = 0; mt < 4; mt++){
#pragma unroll
            for (int r = 0; r < 4; r++){
                int grow = m0 + wm*64 + mt*16 + (l >> 4)*4 + r;
                if (grow < hi){
                    float wgt = w_of[grow];
                    so[(size_t)grow*DM + col] = (acc[mt][nt][r] + bv) * wgt;
                }
            }
        }
    }
}

// ---------------- combine: out[s] = so[p0] + so[p1] ----------------
__global__ __launch_bounds__(256) void combine_kernel(const float* __restrict__ so, const int* __restrict__ pos_of,
                                                      const int* __restrict__ flag, void* __restrict__ out_){
    int fl = *flag;
    int g = blockIdx.x*256 + threadIdx.x;   // S_TOK * 192 chunks of 4
    int s = g / 192, c = (g % 192) * 4;
    int p0 = pos_of[2*s], p1 = pos_of[2*s+1];
    float4 v0 = *(const float4*)&so[(size_t)p0*DM + c];
    float4 v1 = *(const float4*)&so[(size_t)p1*DM + c];
    float4 v; v.x = v0.x+v1.x; v.y = v0.y+v1.y; v.z = v0.z+v1.z; v.w = v0.w+v1.w;
    if (fl){
        *(float4*)((float*)out_ + (size_t)s*DM + c) = v;
    } else {
        short4v o;
        o[0]=(short)f2b(v.x); o[1]=(short)f2b(v.y); o[2]=(short)f2b(v.z); o[3]=(short)f2b(v.w);
        *(short4v*)((u16*)out_ + (size_t)s*DM + c) = o;
    }
}

// ---------------- zero-workspace fallback: one block per token ----------------
__global__ __launch_bounds__(256) void fallback_kernel(const void* __restrict__ x_, const void* __restrict__ wg_,
                                                       const void* __restrict__ w1_, const void* __restrict__ b1_,
                                                       const void* __restrict__ w2_, const void* __restrict__ b2_,
                                                       const int* __restrict__ flag, void* __restrict__ out_){
    int s = blockIdx.x;
    int t = threadIdx.x;
    int fl = flag ? *flag : 1;
    __shared__ float xr[DM];
    __shared__ float hl[DF];
    __shared__ float yl[DM];
    __shared__ float lacc[4*NE];
    __shared__ int   sel_e[2];
    __shared__ float sel_w[2];

    for (int i = t; i < DM; i += 256){
        xr[i] = fl ? ((const float*)x_)[(size_t)s*DM + i] : b2f(((const u16*)x_)[(size_t)s*DM + i]);
        yl[i] = 0.f;
    }
    __syncthreads();

    float acc[NE];
#pragma unroll
    for (int e = 0; e < NE; e++) acc[e] = 0.f;
    for (int d = t*3; d < t*3 + 3; d++){
        float xv = xr[d];
#pragma unroll
        for (int e = 0; e < NE; e++){
            float wv = fl ? ((const float*)wg_)[d*NE + e] : b2f(((const u16*)wg_)[d*NE + e]);
            acc[e] += xv * wv;
        }
    }
#pragma unroll
    for (int e = 0; e < NE; e++){
#pragma unroll
        for (int off = 32; off; off >>= 1) acc[e] += __shfl_down(acc[e], off);
    }
    if ((t & 63) == 0){
        int wv = t >> 6;
#pragma unroll
        for (int e = 0; e < NE; e++) lacc[wv*NE + e] = acc[e];
    }
    __syncthreads();
    if (t == 0){
        float lg[NE];
#pragma unroll
        for (int e = 0; e < NE; e++) lg[e] = lacc[e] + lacc[NE + e] + lacc[2*NE + e] + lacc[3*NE + e];
        int i1 = 0; float v1 = lg[0];
        for (int e = 1; e < NE; e++) if (lg[e] > v1){ v1 = lg[e]; i1 = e; }
        int i2 = -1; float v2 = -1e30f;
        for (int e = 0; e < NE; e++) if (e != i1 && lg[e] > v2){ v2 = lg[e]; i2 = e; }
        if (i2 < 0){ i2 = (i1 + 1) & 7; sel_w[0] = 1.f; sel_w[1] = 0.f; }
        else {
            float e2 = expf(v2 - v1);
            sel_w[0] = 1.f / (1.f + e2);
            sel_w[1] = e2 / (1.f + e2);
        }
        sel_e[0] = i1; sel_e[1] = i2;
    }
    __syncthreads();

    for (int kk = 0; kk < 2; kk++){
        int e = sel_e[kk];
        float wgt = sel_w[kk];
        for (int j = t; j < DF; j += 256){
            float a = fl ? ((const float*)b1_)[e*DF + j] : b2f(((const u16*)b1_)[e*DF + j]);
            if (fl){
                const float* w1p = (const float*)w1_ + (size_t)e * DM * DF;
                for (int k = 0; k < DM; k++) a += xr[k] * w1p[(size_t)k*DF + j];
            } else {
                const u16* w1p = (const u16*)w1_ + (size_t)e * DM * DF;
                for (int k = 0; k < DM; k++) a += xr[k] * b2f(w1p[(size_t)k*DF + j]);
            }
            hl[j] = a > 0.f ? a : 0.f;
        }
        __syncthreads();
        for (int c = t; c < DM; c += 256){
            float a = fl ? ((const float*)b2_)[e*DM + c] : b2f(((const u16*)b2_)[e*DM + c]);
            if (fl){
                const float* w2p = (const float*)w2_ + (size_t)e * DF * DM;
                for (int k = 0; k < DF; k++) a += hl[k] * w2p[(size_t)k*DM + c];
            } else {
                const u16* w2p = (const u16*)w2_ + (size_t)e * DF * DM;
                for (int k = 0; k < DF; k++) a += hl[k] * b2f(w2p[(size_t)k*DM + c]);
            }
            yl[c] += wgt * a;
        }
        __syncthreads();
    }
    for (int c = t; c < DM; c += 256){
        if (fl) ((float*)out_)[(size_t)s*DM + c] = yl[c];
        else    ((u16*)out_)[(size_t)s*DM + c] = f2b(yl[c]);
    }
}

extern "C" void kernel_launch(void* const* d_in, const int* in_sizes, int n_in,
                              void* d_out, int out_size, void* d_ws, size_t ws_size,
                              hipStream_t stream) {
    const void* x  = d_in[0];
    const void* Wg = d_in[1];
    const void* W1 = d_in[2];
    const void* b1 = d_in[3];
    const void* W2 = d_in[4];
    const void* b2 = d_in[5];

    char* ws = (char*)d_ws;
    int*   counts = (int*)(ws + WS_COUNTS);
    int*   cursor = (int*)(ws + WS_CURSOR);
    int*   offs   = (int*)(ws + WS_OFFS);
    int*   flag   = (int*)(ws + WS_FLAG);
    int*   eid    = (int*)(ws + WS_EID);
    float* gw     = (float*)(ws + WS_GW);
    int*   tok_of = (int*)(ws + WS_TOK);
    float* w_of   = (float*)(ws + WS_WOF);
    int*   pos_of = (int*)(ws + WS_POS);

    const size_t soBytes = (size_t)NSLOT * DM * 4;   // fp32 slot outputs, 25.17 MB
    int hs = NSLOT;                                   // h chunk slots (bf16), power of 2
    while (hs > 256 && CTRL_BYTES + soBytes + (size_t)hs*DF*2 > ws_size) hs >>= 1;
    bool grouped = (CTRL_BYTES + soBytes + (size_t)hs*DF*2) <= ws_size;

    if (!grouped){
        if (ws_size >= 256){
            probe_kernel<<<1, 256, 0, stream>>>((const u16*)x, flag);
            fallback_kernel<<<S_TOK, 256, 0, stream>>>(x, Wg, W1, b1, W2, b2, flag, d_out);
        } else {
            fallback_kernel<<<S_TOK, 256, 0, stream>>>(x, Wg, W1, b1, W2, b2, nullptr, d_out);
        }
        return;
    }

    float* so = (float*)(ws + CTRL_BYTES);
    u16*   h  = (u16*)(ws + CTRL_BYTES + soBytes);

    probe_kernel<<<1, 256, 0, stream>>>((const u16*)x, flag);
    init2_kernel<<<1, 64, 0, stream>>>(counts, cursor);
    gate_kernel<<<S_TOK, 64, 0, stream>>>(x, Wg, flag, eid, gw, counts);
    offsets_kernel<<<1, 1, 0, stream>>>(counts, offs, cursor);
    scatter_kernel<<<NSLOT/256, 256, 0, stream>>>(eid, gw, cursor, tok_of, w_of, pos_of);

    int G  = NSLOT / hs;
    int MB = hs / 128;
    for (int g = 0; g < G; g++){
        int s0 = g*hs, s1 = (g+1)*hs;
        gemm1g_kernel<<<dim3(NE*MB, DF/128), 256, 0, stream>>>(x, tok_of, offs, W1, b1, flag, h, s0, s1, MB);
        gemm2g_kernel<<<dim3(NE*MB, DM/128), 256, 0, stream>>>(h, offs, W2, b2, flag, w_of, so, s0, s1, MB);
    }
    combine_kernel<<<S_TOK*(DM/4)/256, 256, 0, stream>>>(so, pos_of, flag, d_out);
}

// Round 5
// 803.478 us; speedup vs baseline: 1.3238x; 1.3238x over previous
//
#include <hip/hip_runtime.h>
#include <math.h>

typedef short short8 __attribute__((ext_vector_type(8)));
typedef short short4v __attribute__((ext_vector_type(4)));
typedef float f32x4 __attribute__((ext_vector_type(4)));
typedef unsigned short u16;
typedef unsigned int u32;

#define S_TOK 4096
#define DM 768
#define DF 3072
#define NE 8
#define NSLOT (S_TOK*2)

// ---- control block ----
#define WS_COUNTS   0
#define WS_CURSOR   64
#define WS_OFFS     128
#define WS_EID      256
#define WS_GW       (WS_EID  + NSLOT*4)
#define WS_TOK      (WS_GW   + NSLOT*4)
#define WS_WOF      (WS_TOK  + NSLOT*4)
#define WS_POS      (WS_WOF  + NSLOT*4)
#define CTRL_BYTES  262144

#if defined(__has_builtin)
#  if __has_builtin(__builtin_amdgcn_global_load_lds)
#    define HAS_GLD 1
#  else
#    define HAS_GLD 0
#  endif
#else
#  define HAS_GLD 0
#endif

#define AS1 __attribute__((address_space(1)))
#define AS3 __attribute__((address_space(3)))

__device__ inline float b2f(u16 v){ u32 u = ((u32)v) << 16; return __builtin_bit_cast(float, u); }
__device__ inline u16 f2b(float f){
    u32 u = __builtin_bit_cast(u32, f);
    u32 r = (u + 0x7fffu + ((u >> 16) & 1u)) >> 16;   // RNE
    return (u16)r;
}
__device__ inline short8 ldcvt8f(const float* p){   // 8 fp32 -> bf16x8
    float4 a = *(const float4*)p;
    float4 b = *(const float4*)(p + 4);
    short8 v;
    v[0]=(short)f2b(a.x); v[1]=(short)f2b(a.y); v[2]=(short)f2b(a.z); v[3]=(short)f2b(a.w);
    v[4]=(short)f2b(b.x); v[5]=(short)f2b(b.y); v[6]=(short)f2b(b.z); v[7]=(short)f2b(b.w);
    return v;
}

// ---------------- init ----------------
__global__ void init2_kernel(int* __restrict__ counts, int* __restrict__ cursor){
    int t = threadIdx.x;
    if (t < 8){ counts[t] = 0; cursor[t] = 0; }
}

// ---------------- x fp32 -> bf16 ----------------
__global__ __launch_bounds__(256) void cvtx_kernel(const float* __restrict__ x, u16* __restrict__ xb){
    int i = (blockIdx.x*256 + threadIdx.x)*8;
    *(short8*)&xb[i] = ldcvt8f(&x[i]);
}

// ---------------- W fp32 [e][K][N] -> bf16 fragment-order [e][ntile][kblk][lane*8] ----------------
// lane l <-> (n = nt*16 + (l&15), k = kblk*32 + (l>>4)*8 + j) == MFMA B-fragment order
__global__ __launch_bounds__(256) void cvtshuf_kernel(const float* __restrict__ W, u16* __restrict__ Ws,
                                                      int Kd, int Nd){
    int kbn = Kd >> 5;
    int kb = blockIdx.x % kbn;
    int nb = blockIdx.x / kbn;        // 128-wide n chunk
    int e  = blockIdx.y;
    const float* Wp = W + (size_t)e * Kd * Nd;
    u16* Wsp       = Ws + (size_t)e * Kd * Nd;
    int t = threadIdx.x;
    __shared__ u16 sh[32*136];
#pragma unroll
    for (int i = 0; i < 2; i++){
        int c = t + 256*i;            // 512 chunks of 8
        int k = c >> 4, nc = c & 15;
        *(short8*)&sh[k*136 + nc*8] = ldcvt8f(&Wp[(size_t)(kb*32 + k)*Nd + nb*128 + nc*8]);
    }
    __syncthreads();
    int w = t >> 6, l = t & 63;
#pragma unroll
    for (int o = 0; o < 2; o++){
        int nt = 2*w + o;
        int n = nt*16 + (l & 15);
        short8 v;
#pragma unroll
        for (int j = 0; j < 8; j++) v[j] = (short)sh[((l >> 4)*8 + j)*136 + n];
        *(short8*)&Wsp[(size_t)(((nb*8 + nt) * kbn + kb) * 512) + l*8] = v;
    }
}

// ---------------- gate ----------------
__global__ __launch_bounds__(64) void gate_kernel(const float* __restrict__ x, const float* __restrict__ Wg,
                                                  int* __restrict__ eid, float* __restrict__ gw,
                                                  int* __restrict__ counts){
    int s = blockIdx.x;
    int l = threadIdx.x;
    float acc[NE];
#pragma unroll
    for (int e = 0; e < NE; e++) acc[e] = 0.f;
    const float* xr = x + (size_t)s * DM;
#pragma unroll
    for (int i = 0; i < DM/64; i++){
        int d = l + 64*i;
        float xv = xr[d];
        float4 w0 = *(const float4*)(Wg + d*NE);
        float4 w1 = *(const float4*)(Wg + d*NE + 4);
        acc[0] += xv*w0.x; acc[1] += xv*w0.y; acc[2] += xv*w0.z; acc[3] += xv*w0.w;
        acc[4] += xv*w1.x; acc[5] += xv*w1.y; acc[6] += xv*w1.z; acc[7] += xv*w1.w;
    }
#pragma unroll
    for (int e = 0; e < NE; e++){
#pragma unroll
        for (int off = 32; off; off >>= 1) acc[e] += __shfl_down(acc[e], off);
    }
    if (l == 0){
        int i1 = 0; float v1 = acc[0];
        for (int e = 1; e < NE; e++) if (acc[e] > v1){ v1 = acc[e]; i1 = e; }
        int i2 = -1; float v2 = -1e30f;
        for (int e = 0; e < NE; e++) if (e != i1 && acc[e] > v2){ v2 = acc[e]; i2 = e; }
        float w0, w1;
        if (i2 < 0){ i2 = (i1 + 1) & 7; w0 = 1.f; w1 = 0.f; }
        else {
            float e2 = expf(v2 - v1);
            w0 = 1.f / (1.f + e2);
            w1 = e2 / (1.f + e2);
        }
        eid[2*s]   = i1; gw[2*s]   = w0;
        eid[2*s+1] = i2; gw[2*s+1] = w1;
        atomicAdd(&counts[i1], 1);
        atomicAdd(&counts[i2], 1);
    }
}

__global__ void offsets_kernel(const int* __restrict__ counts, int* __restrict__ offs, int* __restrict__ cursor){
    if (threadIdx.x == 0 && blockIdx.x == 0){
        int s = 0;
        for (int e = 0; e < NE; e++){ offs[e] = s; cursor[e] = s; s += counts[e]; }
        offs[NE] = s;
    }
}

__global__ __launch_bounds__(256) void scatter_kernel(const int* __restrict__ eid, const float* __restrict__ gw,
                                                      int* __restrict__ cursor, int* __restrict__ tok_of,
                                                      float* __restrict__ w_of, int* __restrict__ pos_of){
    int i = blockIdx.x*256 + threadIdx.x;
    int e = eid[i];
    if (e < 0) e = 0; if (e > 7) e = 7;
    int p = atomicAdd(&cursor[e], 1);
    if (p < 0) p = 0; if (p >= NSLOT) p = NSLOT - 1;
    tok_of[p] = i >> 1;
    w_of[p]  = gw[i];
    pos_of[i] = p;
}

// ---------------- m97-structure GEMM on preshuffled bf16 weights ----------------
// 128x128 tile, BK=32, 4 waves 2x2, 4x4 MFMA 16x16x32. B via global_load_lds(16B)
// into fragment-direct LDS (wave-uniform base + lane*16). A register-prefetched.
template<int KD, int ND, bool IS1>
__global__ __launch_bounds__(256) void gemm_ps_kernel(
        const u16* __restrict__ Asrc, const int* __restrict__ tok_of, const int* __restrict__ offs,
        const u16* __restrict__ Ws, const float* __restrict__ bias, const float* __restrict__ w_of,
        u16* __restrict__ hout, float* __restrict__ so, int s0, int s1, int MB){
    const int KB = KD/32;
    int e  = blockIdx.x / MB;
    int mb = blockIdx.x % MB;
    int lo = offs[e];   if (lo < s0) lo = s0;
    int hi = offs[e+1]; if (hi > s1) hi = s1;
    int m0 = lo + mb*128;
    if (m0 >= hi) return;
    int n0 = blockIdx.y * 128;

    int t = threadIdx.x;
    int w = t >> 6, l = t & 63;
    int wm = w & 1, wn = w >> 1;

    __shared__ u16 As[128*40];   // pitch 40: 2-way bank alias = free (m136)
    __shared__ u16 Bs[8*512];    // fragment-direct: 8 ntiles x (64 lanes x 8)

    int row0 = t >> 2, kc = t & 3;
    int r0 = m0 + row0;        if (r0 > hi-1) r0 = hi-1;
    int r1 = m0 + row0 + 64;   if (r1 > hi-1) r1 = hi-1;
    const u16* a0;
    const u16* a1;
    if (IS1){
        a0 = Asrc + (size_t)tok_of[r0]*KD + kc*8;
        a1 = Asrc + (size_t)tok_of[r1]*KD + kc*8;
    } else {
        a0 = Asrc + (size_t)(r0 - s0)*KD + kc*8;
        a1 = Asrc + (size_t)(r1 - s0)*KD + kc*8;
    }
    u16* as0 = &As[row0*40 + kc*8];
    u16* as1 = &As[(row0 + 64)*40 + kc*8];

    const u16* bsrc0 = Ws + (size_t)e*KD*ND + (size_t)(((n0 >> 4) + 2*w) * KB)*512 + l*8;
    const u16* bsrc1 = bsrc0 + (size_t)KB*512;

    f32x4 acc[4][4];
#pragma unroll
    for (int i = 0; i < 4; i++)
#pragma unroll
        for (int j = 0; j < 4; j++) acc[i][j] = (f32x4){0.f, 0.f, 0.f, 0.f};

    short8 av0 = *(const short8*)a0;
    short8 av1 = *(const short8*)a1;

    for (int kb = 0; kb < KB; kb++){
#if HAS_GLD
        __builtin_amdgcn_global_load_lds((const AS1 u32*)(bsrc0 + (size_t)kb*512),
                                         (AS3 u32*)&Bs[(2*w)*512], 16, 0, 0);
        __builtin_amdgcn_global_load_lds((const AS1 u32*)(bsrc1 + (size_t)kb*512),
                                         (AS3 u32*)&Bs[(2*w + 1)*512], 16, 0, 0);
#else
        short8 b0 = *(const short8*)(bsrc0 + (size_t)kb*512);
        short8 b1 = *(const short8*)(bsrc1 + (size_t)kb*512);
        *(short8*)&Bs[(2*w)*512 + l*8] = b0;
        *(short8*)&Bs[(2*w + 1)*512 + l*8] = b1;
#endif
        *(short8*)as0 = av0;
        *(short8*)as1 = av1;
        __syncthreads();
        if (kb + 1 < KB){          // A prefetch overlaps frag-reads + MFMA
            av0 = *(const short8*)(a0 + (kb+1)*32);
            av1 = *(const short8*)(a1 + (kb+1)*32);
        }
        short8 af[4], bf[4];
#pragma unroll
        for (int mt = 0; mt < 4; mt++)
            af[mt] = *(const short8*)&As[(wm*64 + mt*16 + (l & 15))*40 + (l >> 4)*8];
#pragma unroll
        for (int nt = 0; nt < 4; nt++)
            bf[nt] = *(const short8*)&Bs[(wn*4 + nt)*512 + l*8];
#pragma unroll
        for (int mt = 0; mt < 4; mt++)
#pragma unroll
            for (int nt = 0; nt < 4; nt++)
                acc[mt][nt] = __builtin_amdgcn_mfma_f32_16x16x32_bf16(af[mt], bf[nt], acc[mt][nt], 0, 0, 0);
        __syncthreads();
    }

#pragma unroll
    for (int nt = 0; nt < 4; nt++){
        int col = n0 + wn*64 + nt*16 + (l & 15);
        float bv = bias[e*ND + col];
#pragma unroll
        for (int mt = 0; mt < 4; mt++){
#pragma unroll
            for (int r = 0; r < 4; r++){
                int grow = m0 + wm*64 + mt*16 + (l >> 4)*4 + r;
                if (grow < hi){
                    if (IS1){
                        float v = acc[mt][nt][r] + bv;
                        v = v > 0.f ? v : 0.f;
                        hout[(size_t)(grow - s0)*ND + col] = f2b(v);
                    } else {
                        so[(size_t)grow*ND + col] = (acc[mt][nt][r] + bv) * w_of[grow];
                    }
                }
            }
        }
    }
}

// ---------------- T2 gemm2: fp32-streamed W2, register-prefetched, so bf16 ----------------
__global__ __launch_bounds__(256) void gemm2s_kernel(const u16* __restrict__ h, const int* __restrict__ offs,
                                                     const float* __restrict__ W2, const float* __restrict__ b2,
                                                     const float* __restrict__ w_of, u16* __restrict__ so16,
                                                     int s0, int s1, int MB){
    const int KB = DF/32;   // 96
    int e  = blockIdx.x / MB;
    int mb = blockIdx.x % MB;
    int lo = offs[e];   if (lo < s0) lo = s0;
    int hi = offs[e+1]; if (hi > s1) hi = s1;
    int m0 = lo + mb*128;
    if (m0 >= hi) return;
    int n0 = blockIdx.y * 128;

    int t = threadIdx.x;
    int w = t >> 6, l = t & 63;
    int wm = w & 1, wn = w >> 1;

    __shared__ u16 As[128*40];
    __shared__ u16 Bs[32*136];

    int row0 = t >> 2, kc = t & 3;
    int r0 = m0 + row0;        if (r0 > hi-1) r0 = hi-1;
    int r1 = m0 + row0 + 64;   if (r1 > hi-1) r1 = hi-1;
    const u16* a0 = h + (size_t)(r0 - s0)*DF + kc*8;
    const u16* a1 = h + (size_t)(r1 - s0)*DF + kc*8;
    u16* as0 = &As[row0*40 + kc*8];
    u16* as1 = &As[(row0 + 64)*40 + kc*8];

    const float* wf = W2 + (size_t)e * DF * DM;
    int k0s = t >> 4, ncs = t & 15;

    f32x4 acc[4][4];
#pragma unroll
    for (int i = 0; i < 4; i++)
#pragma unroll
        for (int j = 0; j < 4; j++) acc[i][j] = (f32x4){0.f, 0.f, 0.f, 0.f};

    short8 av0 = *(const short8*)a0;
    short8 av1 = *(const short8*)a1;
    short8 bv0 = ldcvt8f(wf + (size_t)k0s*DM + n0 + ncs*8);
    short8 bv1 = ldcvt8f(wf + (size_t)(k0s + 16)*DM + n0 + ncs*8);

    for (int kb = 0; kb < KB; kb++){
        *(short8*)as0 = av0;
        *(short8*)as1 = av1;
        *(short8*)&Bs[k0s*136 + ncs*8] = bv0;
        *(short8*)&Bs[(k0s + 16)*136 + ncs*8] = bv1;
        __syncthreads();
        if (kb + 1 < KB){
            av0 = *(const short8*)(a0 + (kb+1)*32);
            av1 = *(const short8*)(a1 + (kb+1)*32);
            bv0 = ldcvt8f(wf + (size_t)((kb+1)*32 + k0s)*DM + n0 + ncs*8);
            bv1 = ldcvt8f(wf + (size_t)((kb+1)*32 + k0s + 16)*DM + n0 + ncs*8);
        }
        short8 af[4], bf[4];
#pragma unroll
        for (int mt = 0; mt < 4; mt++)
            af[mt] = *(const short8*)&As[(wm*64 + mt*16 + (l & 15))*40 + (l >> 4)*8];
#pragma unroll
        for (int nt = 0; nt < 4; nt++){
            int nl = wn*64 + nt*16 + (l & 15);
            short8 v;
#pragma unroll
            for (int j = 0; j < 8; j++) v[j] = (short)Bs[((l >> 4)*8 + j)*136 + nl];
            bf[nt] = v;
        }
#pragma unroll
        for (int mt = 0; mt < 4; mt++)
#pragma unroll
            for (int nt = 0; nt < 4; nt++)
                acc[mt][nt] = __builtin_amdgcn_mfma_f32_16x16x32_bf16(af[mt], bf[nt], acc[mt][nt], 0, 0, 0);
        __syncthreads();
    }

#pragma unroll
    for (int nt = 0; nt < 4; nt++){
        int col = n0 + wn*64 + nt*16 + (l & 15);
        float bv = b2[e*DM + col];
#pragma unroll
        for (int mt = 0; mt < 4; mt++){
#pragma unroll
            for (int r = 0; r < 4; r++){
                int grow = m0 + wm*64 + mt*16 + (l >> 4)*4 + r;
                if (grow < hi)
                    so16[(size_t)grow*DM + col] = f2b((acc[mt][nt][r] + bv) * w_of[grow]);
            }
        }
    }
}

// ---------------- combine ----------------
template<bool SO32>
__global__ __launch_bounds__(256) void combine_kernel(const void* __restrict__ so_, const int* __restrict__ pos_of,
                                                      float* __restrict__ out){
    int g = blockIdx.x*256 + threadIdx.x;   // S_TOK * 192 chunks of 4
    int s = g / 192, c = (g % 192) * 4;
    int p0 = pos_of[2*s], p1 = pos_of[2*s+1];
    float4 v0, v1;
    if (SO32){
        const float* so = (const float*)so_;
        v0 = *(const float4*)&so[(size_t)p0*DM + c];
        v1 = *(const float4*)&so[(size_t)p1*DM + c];
    } else {
        const u16* so = (const u16*)so_;
        short4v a = *(const short4v*)&so[(size_t)p0*DM + c];
        short4v b = *(const short4v*)&so[(size_t)p1*DM + c];
        v0 = make_float4(b2f((u16)a[0]), b2f((u16)a[1]), b2f((u16)a[2]), b2f((u16)a[3]));
        v1 = make_float4(b2f((u16)b[0]), b2f((u16)b[1]), b2f((u16)b[2]), b2f((u16)b[3]));
    }
    float4 v; v.x = v0.x+v1.x; v.y = v0.y+v1.y; v.z = v0.z+v1.z; v.w = v0.w+v1.w;
    *(float4*)&out[(size_t)s*DM + c] = v;
}

// ---------------- zero-workspace fallback ----------------
__global__ __launch_bounds__(256) void fallback_kernel(const float* __restrict__ x, const float* __restrict__ Wg,
                                                       const float* __restrict__ W1, const float* __restrict__ b1,
                                                       const float* __restrict__ W2, const float* __restrict__ b2,
                                                       float* __restrict__ out){
    int s = blockIdx.x;
    int t = threadIdx.x;
    __shared__ float xr[DM];
    __shared__ float hl[DF];
    __shared__ float yl[DM];
    __shared__ float lacc[4*NE];
    __shared__ int   sel_e[2];
    __shared__ float sel_w[2];

    for (int i = t; i < DM; i += 256){ xr[i] = x[(size_t)s*DM + i]; yl[i] = 0.f; }
    __syncthreads();

    float acc[NE];
#pragma unroll
    for (int e = 0; e < NE; e++) acc[e] = 0.f;
    for (int d = t*3; d < t*3 + 3; d++){
        float xv = xr[d];
#pragma unroll
        for (int e = 0; e < NE; e++) acc[e] += xv * Wg[d*NE + e];
    }
#pragma unroll
    for (int e = 0; e < NE; e++){
#pragma unroll
        for (int off = 32; off; off >>= 1) acc[e] += __shfl_down(acc[e], off);
    }
    if ((t & 63) == 0){
        int wv = t >> 6;
#pragma unroll
        for (int e = 0; e < NE; e++) lacc[wv*NE + e] = acc[e];
    }
    __syncthreads();
    if (t == 0){
        float lg[NE];
#pragma unroll
        for (int e = 0; e < NE; e++) lg[e] = lacc[e] + lacc[NE + e] + lacc[2*NE + e] + lacc[3*NE + e];
        int i1 = 0; float v1 = lg[0];
        for (int e = 1; e < NE; e++) if (lg[e] > v1){ v1 = lg[e]; i1 = e; }
        int i2 = -1; float v2 = -1e30f;
        for (int e = 0; e < NE; e++) if (e != i1 && lg[e] > v2){ v2 = lg[e]; i2 = e; }
        if (i2 < 0){ i2 = (i1 + 1) & 7; sel_w[0] = 1.f; sel_w[1] = 0.f; }
        else {
            float e2 = expf(v2 - v1);
            sel_w[0] = 1.f / (1.f + e2);
            sel_w[1] = e2 / (1.f + e2);
        }
        sel_e[0] = i1; sel_e[1] = i2;
    }
    __syncthreads();

    for (int kk = 0; kk < 2; kk++){
        int e = sel_e[kk];
        float wgt = sel_w[kk];
        const float* w1p = W1 + (size_t)e * DM * DF;
        for (int j = t; j < DF; j += 256){
            float a = b1[e*DF + j];
            for (int k = 0; k < DM; k++) a += xr[k] * w1p[(size_t)k*DF + j];
            hl[j] = a > 0.f ? a : 0.f;
        }
        __syncthreads();
        const float* w2p = W2 + (size_t)e * DF * DM;
        for (int c = t; c < DM; c += 256){
            float a = b2[e*DM + c];
            for (int k = 0; k < DF; k++) a += hl[k] * w2p[(size_t)k*DM + c];
            yl[c] += wgt * a;
        }
        __syncthreads();
    }
    for (int c = t; c < DM; c += 256) out[(size_t)s*DM + c] = yl[c];
}

extern "C" void kernel_launch(void* const* d_in, const int* in_sizes, int n_in,
                              void* d_out, int out_size, void* d_ws, size_t ws_size,
                              hipStream_t stream) {
    const float* x  = (const float*)d_in[0];
    const float* Wg = (const float*)d_in[1];
    const float* W1 = (const float*)d_in[2];
    const float* b1 = (const float*)d_in[3];
    const float* W2 = (const float*)d_in[4];
    const float* b2 = (const float*)d_in[5];
    float* out = (float*)d_out;

    char* ws = (char*)d_ws;
    int*   counts = (int*)(ws + WS_COUNTS);
    int*   cursor = (int*)(ws + WS_CURSOR);
    int*   offs   = (int*)(ws + WS_OFFS);
    int*   eid    = (int*)(ws + WS_EID);
    float* gw     = (float*)(ws + WS_GW);
    int*   tok_of = (int*)(ws + WS_TOK);
    float* w_of   = (float*)(ws + WS_WOF);
    int*   pos_of = (int*)(ws + WS_POS);

    const size_t xbB  = (size_t)S_TOK*DM*2;          //  6.29 MB
    const size_t wB   = (size_t)NE*DM*DF*2;          // 37.75 MB
    const size_t hB   = (size_t)NSLOT*DF*2;          // 50.33 MB
    const size_t soF  = (size_t)NSLOT*DM*4;          // 25.17 MB
    const size_t soH  = (size_t)NSLOT*DM*2;          // 12.58 MB
    const size_t T1need  = CTRL_BYTES + xbB + 2*wB + soF + hB;   // 157.5 MB
    const size_t T1bneed = CTRL_BYTES + xbB +   wB + soF + hB;   // 119.8 MB

    if (ws_size >= T1need){
        // ---- T1: both weights preshuffled, G=1 ----
        u16*   xb  = (u16*)(ws + CTRL_BYTES);
        u16*   W1s = (u16*)(ws + CTRL_BYTES + xbB);
        u16*   W2s = (u16*)(ws + CTRL_BYTES + xbB + wB);
        float* so  = (float*)(ws + CTRL_BYTES + xbB + 2*wB);
        u16*   h   = (u16*)(ws + CTRL_BYTES + xbB + 2*wB + soF);

        cvtx_kernel<<<S_TOK*DM/8/256, 256, 0, stream>>>(x, xb);
        cvtshuf_kernel<<<dim3((DM/32)*(DF/128), NE), 256, 0, stream>>>(W1, W1s, DM, DF);
        cvtshuf_kernel<<<dim3((DF/32)*(DM/128), NE), 256, 0, stream>>>(W2, W2s, DF, DM);
        init2_kernel<<<1, 64, 0, stream>>>(counts, cursor);
        gate_kernel<<<S_TOK, 64, 0, stream>>>(x, Wg, eid, gw, counts);
        offsets_kernel<<<1, 1, 0, stream>>>(counts, offs, cursor);
        scatter_kernel<<<NSLOT/256, 256, 0, stream>>>(eid, gw, cursor, tok_of, w_of, pos_of);
        gemm_ps_kernel<DM, DF, true ><<<dim3(NE*64, DF/128), 256, 0, stream>>>(xb, tok_of, offs, W1s, b1, nullptr, h, nullptr, 0, NSLOT, 64);
        gemm_ps_kernel<DF, DM, false><<<dim3(NE*64, DM/128), 256, 0, stream>>>(h, tok_of, offs, W2s, b2, w_of, nullptr, so, 0, NSLOT, 64);
        combine_kernel<true><<<S_TOK*(DM/4)/256, 256, 0, stream>>>(so, pos_of, out);
    } else if (ws_size >= T1bneed){
        // ---- T1b: one shared preshuffle buffer, sequential W1 -> W2 ----
        u16*   xb  = (u16*)(ws + CTRL_BYTES);
        u16*   Wsh = (u16*)(ws + CTRL_BYTES + xbB);
        float* so  = (float*)(ws + CTRL_BYTES + xbB + wB);
        u16*   h   = (u16*)(ws + CTRL_BYTES + xbB + wB + soF);

        cvtx_kernel<<<S_TOK*DM/8/256, 256, 0, stream>>>(x, xb);
        init2_kernel<<<1, 64, 0, stream>>>(counts, cursor);
        gate_kernel<<<S_TOK, 64, 0, stream>>>(x, Wg, eid, gw, counts);
        offsets_kernel<<<1, 1, 0, stream>>>(counts, offs, cursor);
        scatter_kernel<<<NSLOT/256, 256, 0, stream>>>(eid, gw, cursor, tok_of, w_of, pos_of);
        cvtshuf_kernel<<<dim3((DM/32)*(DF/128), NE), 256, 0, stream>>>(W1, Wsh, DM, DF);
        gemm_ps_kernel<DM, DF, true ><<<dim3(NE*64, DF/128), 256, 0, stream>>>(xb, tok_of, offs, Wsh, b1, nullptr, h, nullptr, 0, NSLOT, 64);
        cvtshuf_kernel<<<dim3((DF/32)*(DM/128), NE), 256, 0, stream>>>(W2, Wsh, DF, DM);
        gemm_ps_kernel<DF, DM, false><<<dim3(NE*64, DM/128), 256, 0, stream>>>(h, tok_of, offs, Wsh, b2, w_of, nullptr, so, 0, NSLOT, 64);
        combine_kernel<true><<<S_TOK*(DM/4)/256, 256, 0, stream>>>(so, pos_of, out);
    } else {
        // ---- T2: preshuffled W1 + streamed fp32 W2; h chunked; so bf16 ----
        size_t fixed = CTRL_BYTES + xbB + wB + soH;
        int hs = NSLOT;
        while (hs > 256 && fixed + (size_t)hs*DF*2 > ws_size) hs >>= 1;
        if (fixed + (size_t)hs*DF*2 > ws_size){
            fallback_kernel<<<S_TOK, 256, 0, stream>>>(x, Wg, W1, b1, W2, b2, out);
            return;
        }
        u16* xb   = (u16*)(ws + CTRL_BYTES);
        u16* W1s  = (u16*)(ws + CTRL_BYTES + xbB);
        u16* so16 = (u16*)(ws + CTRL_BYTES + xbB + wB);
        u16* h    = (u16*)(ws + CTRL_BYTES + xbB + wB + soH);

        cvtx_kernel<<<S_TOK*DM/8/256, 256, 0, stream>>>(x, xb);
        cvtshuf_kernel<<<dim3((DM/32)*(DF/128), NE), 256, 0, stream>>>(W1, W1s, DM, DF);
        init2_kernel<<<1, 64, 0, stream>>>(counts, cursor);
        gate_kernel<<<S_TOK, 64, 0, stream>>>(x, Wg, eid, gw, counts);
        offsets_kernel<<<1, 1, 0, stream>>>(counts, offs, cursor);
        scatter_kernel<<<NSLOT/256, 256, 0, stream>>>(eid, gw, cursor, tok_of, w_of, pos_of);

        int G  = NSLOT / hs;
        int MB = hs / 128;
        for (int g = 0; g < G; g++){
            int s0 = g*hs, s1 = (g+1)*hs;
            gemm_ps_kernel<DM, DF, true><<<dim3(NE*MB, DF/128), 256, 0, stream>>>(xb, tok_of, offs, W1s, b1, nullptr, h, nullptr, s0, s1, MB);
            gemm2s_kernel<<<dim3(NE*MB, DM/128), 256, 0, stream>>>(h, offs, W2, b2, w_of, so16, s0, s1, MB);
        }
        combine_kernel<false><<<S_TOK*(DM/4)/256, 256, 0, stream>>>(so16, pos_of, out);
    }
}

// Round 6
// 608.030 us; speedup vs baseline: 1.7494x; 1.3214x over previous
//
#include <hip/hip_runtime.h>
#include <math.h>

typedef short short8 __attribute__((ext_vector_type(8)));
typedef float f32x4 __attribute__((ext_vector_type(4)));
typedef unsigned short u16;
typedef unsigned int u32;

#define S_TOK 4096
#define DM 768
#define DF 3072
#define NE 8
#define NSLOT (S_TOK*2)      // 8192 real slots
#define PSLOT 9216           // padded capacity (8192 + 8*127 rounded up)
#define MBMAX 72             // PSLOT/128

// ---- control block ----
#define WS_COUNTS   0        // 8 ints
#define WS_CURSOR   64       // 8 ints
#define WS_OFFS     128      // 9 ints (padded expert starts)
#define WS_MBE      192      // MBMAX ints (mb -> expert, -1 = dead)
#define WS_EID      512      // NSLOT ints
#define WS_GW       (WS_EID + NSLOT*4)
#define WS_TOK      (WS_GW  + NSLOT*4)      // PSLOT ints
#define WS_WOF      (WS_TOK + PSLOT*4)      // PSLOT floats
#define CTRL_BYTES  262144

#define AS1 __attribute__((address_space(1)))
#define AS3 __attribute__((address_space(3)))
#define GLDS16(g, s) __builtin_amdgcn_global_load_lds((const AS1 u32*)(g), (AS3 u32*)(s), 16, 0, 0)

__device__ inline float b2f(u16 v){ u32 u = ((u32)v) << 16; return __builtin_bit_cast(float, u); }
__device__ inline u16 f2b(float f){
    u32 u = __builtin_bit_cast(u32, f);
    u32 r = (u + 0x7fffu + ((u >> 16) & 1u)) >> 16;   // RNE
    return (u16)r;
}
__device__ inline short8 ldcvt8f(const float* p){
    float4 a = *(const float4*)p;
    float4 b = *(const float4*)(p + 4);
    short8 v;
    v[0]=(short)f2b(a.x); v[1]=(short)f2b(a.y); v[2]=(short)f2b(a.z); v[3]=(short)f2b(a.w);
    v[4]=(short)f2b(b.x); v[5]=(short)f2b(b.y); v[6]=(short)f2b(b.z); v[7]=(short)f2b(b.w);
    return v;
}

// ---------------- zero out (12.6 MB) ----------------
__global__ __launch_bounds__(256) void zero_kernel(float* __restrict__ p){
    int i = (blockIdx.x*256 + threadIdx.x)*4;
    *(float4*)&p[i] = make_float4(0.f,0.f,0.f,0.f);
}

__global__ void init2_kernel(int* __restrict__ counts, int* __restrict__ cursor){
    int t = threadIdx.x;
    if (t < 8){ counts[t] = 0; cursor[t] = 0; }
}

// ---------------- gate ----------------
__global__ __launch_bounds__(64) void gate_kernel(const float* __restrict__ x, const float* __restrict__ Wg,
                                                  int* __restrict__ eid, float* __restrict__ gw,
                                                  int* __restrict__ counts){
    int s = blockIdx.x;
    int l = threadIdx.x;
    float acc[NE];
#pragma unroll
    for (int e = 0; e < NE; e++) acc[e] = 0.f;
    const float* xr = x + (size_t)s * DM;
#pragma unroll
    for (int i = 0; i < DM/64; i++){
        int d = l + 64*i;
        float xv = xr[d];
        float4 w0 = *(const float4*)(Wg + d*NE);
        float4 w1 = *(const float4*)(Wg + d*NE + 4);
        acc[0] += xv*w0.x; acc[1] += xv*w0.y; acc[2] += xv*w0.z; acc[3] += xv*w0.w;
        acc[4] += xv*w1.x; acc[5] += xv*w1.y; acc[6] += xv*w1.z; acc[7] += xv*w1.w;
    }
#pragma unroll
    for (int e = 0; e < NE; e++){
#pragma unroll
        for (int off = 32; off; off >>= 1) acc[e] += __shfl_down(acc[e], off);
    }
    if (l == 0){
        int i1 = 0; float v1 = acc[0];
        for (int e = 1; e < NE; e++) if (acc[e] > v1){ v1 = acc[e]; i1 = e; }
        int i2 = -1; float v2 = -1e30f;
        for (int e = 0; e < NE; e++) if (e != i1 && acc[e] > v2){ v2 = acc[e]; i2 = e; }
        float w0, w1;
        if (i2 < 0){ i2 = (i1 + 1) & 7; w0 = 1.f; w1 = 0.f; }
        else {
            float e2 = expf(v2 - v1);
            w0 = 1.f / (1.f + e2);
            w1 = e2 / (1.f + e2);
        }
        eid[2*s]   = i1; gw[2*s]   = w0;
        eid[2*s+1] = i2; gw[2*s+1] = w1;
        atomicAdd(&counts[i1], 1);
        atomicAdd(&counts[i2], 1);
    }
}

// ---------------- offsets with capacity padding + mb->expert map ----------------
__global__ void offsets_kernel(const int* __restrict__ counts, int* __restrict__ offs,
                               int* __restrict__ cursor, int* __restrict__ mbe){
    if (threadIdx.x == 0 && blockIdx.x == 0){
        int P = 0;
        for (int e = 0; e < NE; e++){
            offs[e] = P; cursor[e] = P;
            int padded = ((counts[e] + 127) >> 7) << 7;
            for (int mb = P >> 7; mb < (P + padded) >> 7; mb++) mbe[mb] = e;
            P += padded;
        }
        offs[NE] = P;
        for (int mb = P >> 7; mb < MBMAX; mb++) mbe[mb] = -1;
    }
}

__global__ __launch_bounds__(256) void scatter_kernel(const int* __restrict__ eid, const float* __restrict__ gw,
                                                      int* __restrict__ cursor, int* __restrict__ tok_of,
                                                      float* __restrict__ w_of){
    int i = blockIdx.x*256 + threadIdx.x;
    int e = eid[i];
    if (e < 0) e = 0; if (e > 7) e = 7;
    int p = atomicAdd(&cursor[e], 1);
    if (p < 0) p = 0; if (p >= PSLOT) p = PSLOT - 1;
    tok_of[p] = i >> 1;
    w_of[p]  = gw[i];
}

// fill pad rows: token 0, weight 0
__global__ __launch_bounds__(256) void padfill_kernel(const int* __restrict__ counts, const int* __restrict__ offs,
                                                      const int* __restrict__ mbe, int* __restrict__ tok_of,
                                                      float* __restrict__ w_of){
    int p = blockIdx.x*256 + threadIdx.x;   // 0..PSLOT
    int e = mbe[p >> 7];
    if (e < 0){ tok_of[p] = 0; w_of[p] = 0.f; return; }
    if (p >= offs[e] + counts[e]){ tok_of[p] = 0; w_of[p] = 0.f; }
}

// ---------------- x fp32 -> bf16 ----------------
__global__ __launch_bounds__(256) void cvtx_kernel(const float* __restrict__ x, u16* __restrict__ xb){
    int i = (blockIdx.x*256 + threadIdx.x)*8;
    *(short8*)&xb[i] = ldcvt8f(&x[i]);
}

// ---------------- W fp32 [e][K][N] -> bf16 fragment order [e][ntile][kblk][lane*8] ----------------
__global__ __launch_bounds__(256) void cvtshuf_kernel(const float* __restrict__ W, u16* __restrict__ Ws,
                                                      int Kd, int Nd){
    int kbn = Kd >> 5;
    int kb = blockIdx.x % kbn;
    int nb = blockIdx.x / kbn;
    int e  = blockIdx.y;
    const float* Wp = W + (size_t)e * Kd * Nd;
    u16* Wsp       = Ws + (size_t)e * Kd * Nd;
    int t = threadIdx.x;
    __shared__ u16 sh[32*136];
#pragma unroll
    for (int i = 0; i < 2; i++){
        int c = t + 256*i;
        int k = c >> 4, nc = c & 15;
        *(short8*)&sh[k*136 + nc*8] = ldcvt8f(&Wp[(size_t)(kb*32 + k)*Nd + nb*128 + nc*8]);
    }
    __syncthreads();
    int w = t >> 6, l = t & 63;
#pragma unroll
    for (int o = 0; o < 2; o++){
        int nt = 2*w + o;
        int n = nt*16 + (l & 15);
        short8 v;
#pragma unroll
        for (int j = 0; j < 8; j++) v[j] = (short)sh[((l >> 4)*8 + j)*136 + n];
        *(short8*)&Wsp[(size_t)(((nb*8 + nt) * kbn + kb) * 512) + l*8] = v;
    }
}

// ---------------- GEMM1: h = relu(x[tok] @ W1[e] + b1[e]); unroll-2, dual B buffers ----------------
// grid.x = MBMAX*24; bid = mb*24 + by -> XCD = by%8 (B strips L2-local per XCD)
__global__ __launch_bounds__(256) void gemm1u_kernel(const u16* __restrict__ xb, const int* __restrict__ tok_of,
                                                     const int* __restrict__ mbe, const u16* __restrict__ W1s,
                                                     const float* __restrict__ b1, u16* __restrict__ h){
    const int KB = DM/32;     // 24 kblks
    const int KB2 = DM/64;    // 12 double-steps
    int bid = blockIdx.x;
    int by = bid % 24, mb = bid / 24;
    int e = mbe[mb];
    if (e < 0) return;
    int m0 = mb*128, n0 = by*128;

    int t = threadIdx.x;
    int w = t >> 6, l = t & 63;
    int wm = w & 1, wn = w >> 1;

    __shared__ u16 As[128*72];     // 128 rows x 64 cols + 8 pad
    __shared__ u16 Bs[2*8*512];    // [ks][ntile][lane*8]

    int row0 = t >> 2, kc = t & 3;
    const u16* a0 = xb + (size_t)tok_of[m0 + row0]*DM + kc*8;
    const u16* a1 = xb + (size_t)tok_of[m0 + row0 + 64]*DM + kc*8;
    u16* as0 = &As[row0*72 + kc*8];
    u16* as1 = &As[(row0 + 64)*72 + kc*8];

    const u16* bbase = W1s + (size_t)e*DM*DF + (size_t)(((n0 >> 4) + 2*w)*KB)*512 + l*8;
    // ntile o: + o*KB*512 ; kblk: + kblk*512

    f32x4 acc[4][4];
#pragma unroll
    for (int i = 0; i < 4; i++)
#pragma unroll
        for (int j = 0; j < 4; j++) acc[i][j] = (f32x4){0.f,0.f,0.f,0.f};

    short8 av0a = *(const short8*)a0;
    short8 av0b = *(const short8*)(a0 + 32);
    short8 av1a = *(const short8*)a1;
    short8 av1b = *(const short8*)(a1 + 32);

    for (int kb2 = 0; kb2 < KB2; kb2++){
        GLDS16(bbase + (size_t)(2*kb2)*512,              &Bs[(2*w)*512]);
        GLDS16(bbase + (size_t)(2*kb2+1)*512,            &Bs[4096 + (2*w)*512]);
        GLDS16(bbase + (size_t)KB*512 + (size_t)(2*kb2)*512,   &Bs[(2*w+1)*512]);
        GLDS16(bbase + (size_t)KB*512 + (size_t)(2*kb2+1)*512, &Bs[4096 + (2*w+1)*512]);
        *(short8*)as0 = av0a;
        *(short8*)(as0 + 32) = av0b;
        *(short8*)as1 = av1a;
        *(short8*)(as1 + 32) = av1b;
        __syncthreads();
        if (kb2 + 1 < KB2){
            av0a = *(const short8*)(a0 + (kb2+1)*64);
            av0b = *(const short8*)(a0 + (kb2+1)*64 + 32);
            av1a = *(const short8*)(a1 + (kb2+1)*64);
            av1b = *(const short8*)(a1 + (kb2+1)*64 + 32);
        }
#pragma unroll
        for (int ks = 0; ks < 2; ks++){
            short8 af[4], bf[4];
#pragma unroll
            for (int mt = 0; mt < 4; mt++)
                af[mt] = *(const short8*)&As[(wm*64 + mt*16 + (l & 15))*72 + ks*32 + (l >> 4)*8];
#pragma unroll
            for (int nt = 0; nt < 4; nt++)
                bf[nt] = *(const short8*)&Bs[ks*4096 + (wn*4 + nt)*512 + l*8];
#pragma unroll
            for (int mt = 0; mt < 4; mt++)
#pragma unroll
                for (int nt = 0; nt < 4; nt++)
                    acc[mt][nt] = __builtin_amdgcn_mfma_f32_16x16x32_bf16(af[mt], bf[nt], acc[mt][nt], 0, 0, 0);
        }
        __syncthreads();
    }

#pragma unroll
    for (int nt = 0; nt < 4; nt++){
        int col = n0 + wn*64 + nt*16 + (l & 15);
        float bv = b1[e*DF + col];
#pragma unroll
        for (int mt = 0; mt < 4; mt++){
#pragma unroll
            for (int r = 0; r < 4; r++){
                int grow = m0 + wm*64 + mt*16 + (l >> 4)*4 + r;
                float v = acc[mt][nt][r] + bv;
                v = v > 0.f ? v : 0.f;
                h[(size_t)grow*DF + col] = f2b(v);
            }
        }
    }
}

// ---------------- GEMM2: out[tok] += w*(h @ W2[e] + b2[e]); split-K2, atomic epilogue ----------------
// grid.x = 2*6*MBMAX; bid = sp*432 + by*72 + mb -> XCD = mb%8 (A rows L2-local per XCD)
__global__ __launch_bounds__(256) void gemm2u_kernel(const u16* __restrict__ h, const int* __restrict__ tok_of,
                                                     const int* __restrict__ mbe, const u16* __restrict__ W2s,
                                                     const float* __restrict__ b2, const float* __restrict__ w_of,
                                                     float* __restrict__ out){
    const int KB = DF/32;     // 96 kblks total
    const int KB2 = 24;       // 48 kblks per split / 2
    int bid = blockIdx.x;
    int mb = bid % MBMAX;
    int by = (bid / MBMAX) % 6;
    int sp = bid / (6*MBMAX);
    int e = mbe[mb];
    if (e < 0) return;
    int m0 = mb*128, n0 = by*128;
    int kbase = sp*48;        // kblk offset

    int t = threadIdx.x;
    int w = t >> 6, l = t & 63;
    int wm = w & 1, wn = w >> 1;

    __shared__ u16 As[128*72];
    __shared__ u16 Bs[2*8*512];

    int row0 = t >> 2, kc = t & 3;
    const u16* a0 = h + (size_t)(m0 + row0)*DF + kbase*32 + kc*8;
    const u16* a1 = h + (size_t)(m0 + row0 + 64)*DF + kbase*32 + kc*8;
    u16* as0 = &As[row0*72 + kc*8];
    u16* as1 = &As[(row0 + 64)*72 + kc*8];

    const u16* bbase = W2s + (size_t)e*DF*DM + (size_t)(((n0 >> 4) + 2*w)*KB + kbase)*512 + l*8;

    f32x4 acc[4][4];
#pragma unroll
    for (int i = 0; i < 4; i++)
#pragma unroll
        for (int j = 0; j < 4; j++) acc[i][j] = (f32x4){0.f,0.f,0.f,0.f};

    short8 av0a = *(const short8*)a0;
    short8 av0b = *(const short8*)(a0 + 32);
    short8 av1a = *(const short8*)a1;
    short8 av1b = *(const short8*)(a1 + 32);

    for (int kb2 = 0; kb2 < KB2; kb2++){
        GLDS16(bbase + (size_t)(2*kb2)*512,              &Bs[(2*w)*512]);
        GLDS16(bbase + (size_t)(2*kb2+1)*512,            &Bs[4096 + (2*w)*512]);
        GLDS16(bbase + (size_t)KB*512 + (size_t)(2*kb2)*512,   &Bs[(2*w+1)*512]);
        GLDS16(bbase + (size_t)KB*512 + (size_t)(2*kb2+1)*512, &Bs[4096 + (2*w+1)*512]);
        *(short8*)as0 = av0a;
        *(short8*)(as0 + 32) = av0b;
        *(short8*)as1 = av1a;
        *(short8*)(as1 + 32) = av1b;
        __syncthreads();
        if (kb2 + 1 < KB2){
            av0a = *(const short8*)(a0 + (kb2+1)*64);
            av0b = *(const short8*)(a0 + (kb2+1)*64 + 32);
            av1a = *(const short8*)(a1 + (kb2+1)*64);
            av1b = *(const short8*)(a1 + (kb2+1)*64 + 32);
        }
#pragma unroll
        for (int ks = 0; ks < 2; ks++){
            short8 af[4], bf[4];
#pragma unroll
            for (int mt = 0; mt < 4; mt++)
                af[mt] = *(const short8*)&As[(wm*64 + mt*16 + (l & 15))*72 + ks*32 + (l >> 4)*8];
#pragma unroll
            for (int nt = 0; nt < 4; nt++)
                bf[nt] = *(const short8*)&Bs[ks*4096 + (wn*4 + nt)*512 + l*8];
#pragma unroll
            for (int mt = 0; mt < 4; mt++)
#pragma unroll
                for (int nt = 0; nt < 4; nt++)
                    acc[mt][nt] = __builtin_amdgcn_mfma_f32_16x16x32_bf16(af[mt], bf[nt], acc[mt][nt], 0, 0, 0);
        }
        __syncthreads();
    }

#pragma unroll
    for (int nt = 0; nt < 4; nt++){
        int col = n0 + wn*64 + nt*16 + (l & 15);
        float bv = (sp == 0) ? b2[e*DM + col] : 0.f;
#pragma unroll
        for (int mt = 0; mt < 4; mt++){
#pragma unroll
            for (int r = 0; r < 4; r++){
                int grow = m0 + wm*64 + mt*16 + (l >> 4)*4 + r;
                float wgt = w_of[grow];
                int tok = tok_of[grow];
                atomicAdd(&out[(size_t)tok*DM + col], (acc[mt][nt][r] + bv) * wgt);
            }
        }
    }
}

// ---------------- zero-workspace fallback ----------------
__global__ __launch_bounds__(256) void fallback_kernel(const float* __restrict__ x, const float* __restrict__ Wg,
                                                       const float* __restrict__ W1, const float* __restrict__ b1,
                                                       const float* __restrict__ W2, const float* __restrict__ b2,
                                                       float* __restrict__ out){
    int s = blockIdx.x;
    int t = threadIdx.x;
    __shared__ float xr[DM];
    __shared__ float hl[DF];
    __shared__ float yl[DM];
    __shared__ float lacc[4*NE];
    __shared__ int   sel_e[2];
    __shared__ float sel_w[2];

    for (int i = t; i < DM; i += 256){ xr[i] = x[(size_t)s*DM + i]; yl[i] = 0.f; }
    __syncthreads();

    float acc[NE];
#pragma unroll
    for (int e = 0; e < NE; e++) acc[e] = 0.f;
    for (int d = t*3; d < t*3 + 3; d++){
        float xv = xr[d];
#pragma unroll
        for (int e = 0; e < NE; e++) acc[e] += xv * Wg[d*NE + e];
    }
#pragma unroll
    for (int e = 0; e < NE; e++){
#pragma unroll
        for (int off = 32; off; off >>= 1) acc[e] += __shfl_down(acc[e], off);
    }
    if ((t & 63) == 0){
        int wv = t >> 6;
#pragma unroll
        for (int e = 0; e < NE; e++) lacc[wv*NE + e] = acc[e];
    }
    __syncthreads();
    if (t == 0){
        float lg[NE];
#pragma unroll
        for (int e = 0; e < NE; e++) lg[e] = lacc[e] + lacc[NE + e] + lacc[2*NE + e] + lacc[3*NE + e];
        int i1 = 0; float v1 = lg[0];
        for (int e = 1; e < NE; e++) if (lg[e] > v1){ v1 = lg[e]; i1 = e; }
        int i2 = -1; float v2 = -1e30f;
        for (int e = 0; e < NE; e++) if (e != i1 && lg[e] > v2){ v2 = lg[e]; i2 = e; }
        if (i2 < 0){ i2 = (i1 + 1) & 7; sel_w[0] = 1.f; sel_w[1] = 0.f; }
        else {
            float e2 = expf(v2 - v1);
            sel_w[0] = 1.f / (1.f + e2);
            sel_w[1] = e2 / (1.f + e2);
        }
        sel_e[0] = i1; sel_e[1] = i2;
    }
    __syncthreads();

    for (int kk = 0; kk < 2; kk++){
        int e = sel_e[kk];
        float wgt = sel_w[kk];
        const float* w1p = W1 + (size_t)e * DM * DF;
        for (int j = t; j < DF; j += 256){
            float a = b1[e*DF + j];
            for (int k = 0; k < DM; k++) a += xr[k] * w1p[(size_t)k*DF + j];
            hl[j] = a > 0.f ? a : 0.f;
        }
        __syncthreads();
        const float* w2p = W2 + (size_t)e * DF * DM;
        for (int c = t; c < DM; c += 256){
            float a = b2[e*DM + c];
            for (int k = 0; k < DF; k++) a += hl[k] * w2p[(size_t)k*DM + c];
            yl[c] += wgt * a;
        }
        __syncthreads();
    }
    for (int c = t; c < DM; c += 256) out[(size_t)s*DM + c] = yl[c];
}

extern "C" void kernel_launch(void* const* d_in, const int* in_sizes, int n_in,
                              void* d_out, int out_size, void* d_ws, size_t ws_size,
                              hipStream_t stream) {
    const float* x  = (const float*)d_in[0];
    const float* Wg = (const float*)d_in[1];
    const float* W1 = (const float*)d_in[2];
    const float* b1 = (const float*)d_in[3];
    const float* W2 = (const float*)d_in[4];
    const float* b2 = (const float*)d_in[5];
    float* out = (float*)d_out;

    char* ws = (char*)d_ws;
    int*   counts = (int*)(ws + WS_COUNTS);
    int*   cursor = (int*)(ws + WS_CURSOR);
    int*   offs   = (int*)(ws + WS_OFFS);
    int*   mbe    = (int*)(ws + WS_MBE);
    int*   eid    = (int*)(ws + WS_EID);
    float* gw     = (float*)(ws + WS_GW);
    int*   tok_of = (int*)(ws + WS_TOK);
    float* w_of   = (float*)(ws + WS_WOF);

    const size_t xbB = (size_t)S_TOK*DM*2;           //  6.29 MB
    const size_t wB  = (size_t)NE*DM*DF*2;           // 37.75 MB each
    const size_t hB  = (size_t)PSLOT*DF*2;           // 56.62 MB
    const size_t need = CTRL_BYTES + xbB + 2*wB + hB;  // 138.7 MB

    if (ws_size < need){
        fallback_kernel<<<S_TOK, 256, 0, stream>>>(x, Wg, W1, b1, W2, b2, out);
        return;
    }

    u16* xb  = (u16*)(ws + CTRL_BYTES);
    u16* W1s = (u16*)(ws + CTRL_BYTES + xbB);
    u16* W2s = (u16*)(ws + CTRL_BYTES + xbB + wB);
    u16* h   = (u16*)(ws + CTRL_BYTES + xbB + 2*wB);

    zero_kernel<<<(S_TOK*DM/4)/256, 256, 0, stream>>>(out);
    init2_kernel<<<1, 64, 0, stream>>>(counts, cursor);
    cvtx_kernel<<<S_TOK*DM/8/256, 256, 0, stream>>>(x, xb);
    cvtshuf_kernel<<<dim3((DM/32)*(DF/128), NE), 256, 0, stream>>>(W1, W1s, DM, DF);
    cvtshuf_kernel<<<dim3((DF/32)*(DM/128), NE), 256, 0, stream>>>(W2, W2s, DF, DM);
    gate_kernel<<<S_TOK, 64, 0, stream>>>(x, Wg, eid, gw, counts);
    offsets_kernel<<<1, 1, 0, stream>>>(counts, offs, cursor, mbe);
    scatter_kernel<<<NSLOT/256, 256, 0, stream>>>(eid, gw, cursor, tok_of, w_of);
    padfill_kernel<<<PSLOT/256, 256, 0, stream>>>(counts, offs, mbe, tok_of, w_of);

    gemm1u_kernel<<<MBMAX*24, 256, 0, stream>>>(xb, tok_of, mbe, W1s, b1, h);
    gemm2u_kernel<<<2*6*MBMAX, 256, 0, stream>>>(h, tok_of, mbe, W2s, b2, w_of, out);
}